// Round 1
// baseline (1357.638 us; speedup 1.0000x reference)
//
#include <hip/hip_runtime.h>

// Problem constants (from reference): b=2, m=1024, n=64 tokens, DIM=512,
// HEADS=8, DIM_HEAD=64, HIDDEN=512. BM = b*m = 2048 sequence-groups.
#define NBM   2048
#define NTOK  64
#define KDIM  512
#define NHEAD 8

typedef __attribute__((ext_vector_type(8))) short short8;   // 8 x bf16 = 4 VGPRs (MFMA A/B frag)
typedef __attribute__((ext_vector_type(4))) float floatx4;  // MFMA C/D frag

__device__ __forceinline__ unsigned short f2bf(float f) {
    union { float f; unsigned u; } v; v.f = f;
    unsigned r = v.u + 0x7FFFu + ((v.u >> 16) & 1u);  // round-to-nearest-even
    return (unsigned short)(r >> 16);
}

// ---------------------------------------------------------------------------
// Prep: transpose fp32 weight (K x C, row-major) into bf16 wT (C x K).
// Makes the GEMM B-operand K-major so LDS fragment reads are contiguous b128.
// ---------------------------------------------------------------------------
__global__ __launch_bounds__(256) void transpose_w(const float* __restrict__ w,
                                                   unsigned short* __restrict__ wT,
                                                   int K, int C) {
    __shared__ float tile[32][33];
    int kb = blockIdx.x * 32, cb = blockIdx.y * 32;
    int tx = threadIdx.x & 31, ty = threadIdx.x >> 5;   // 32 x 8
    for (int i = ty; i < 32; i += 8)
        tile[i][tx] = w[(size_t)(kb + i) * C + cb + tx];
    __syncthreads();
    for (int i = ty; i < 32; i += 8)
        wT[(size_t)(cb + i) * K + kb + tx] = f2bf(tile[tx][i]);
}

// ---------------------------------------------------------------------------
// Fused: qkv = x @ w_qkv (head slice), scale+rotary(q), rotary(k),
//        sim = q k^T + pos_bias, mask/softmax, out = attn @ v  -> ws (bf16)
// One block per (bm, head). 256 threads = 4 waves; wave w owns token rows
// 16w..16w+15. MFMA 16x16x32 bf16; verified layouts:
//   A[m=lane&15][k=quad*8+j], B[k=quad*8+j][n=lane&15], C row=quad*4+reg col=lane&15.
// ---------------------------------------------------------------------------
__global__ __launch_bounds__(256) void fused_qkv_attn(
        const float* __restrict__ x,              // (2048, 64, 512) fp32
        const float* __restrict__ pos_bias,       // (8, 64, 64) fp32
        const unsigned short* __restrict__ wqkvT, // (1536, 512) bf16, K-major
        const int* __restrict__ mask,             // (2,) int
        unsigned short* __restrict__ attn_out)    // (2048*64, 512) bf16
{
    const int blk = blockIdx.x;
    const int h   = blk & 7;
    const int bm  = blk >> 3;
    const int b   = bm >> 10;
    const int tid = threadIdx.x;
    const int wv = tid >> 6, lane = tid & 63, quad = lane >> 4, l16 = lane & 15;

    // LDS: staging (g) and attention buffers (a) time-share the same 36 KB.
    // +8 bf16 row pad: quad-strided b128 reads -> 2-way bank alias (free).
    __shared__ union SMem {
        struct { unsigned short xs[64][72]; unsigned short wT[192][72]; } g;   // 36864 B
        struct { unsigned short qs[64][72]; unsigned short ks[64][72];
                 unsigned short vt[64][72]; unsigned short at[64][72]; } a;    // 36864 B
    } sm;

    floatx4 acc[12];                       // 64 x 192 output: 12 col-tiles / wave
    #pragma unroll
    for (int i = 0; i < 12; i++) acc[i] = floatx4{0.f, 0.f, 0.f, 0.f};

    const float* xbase = x + (size_t)bm * (NTOK * KDIM);

    // ---- QKV GEMM: K = 512 in 8 steps of BK=64 ----
    for (int kk = 0; kk < 8; kk++) {
        if (kk) __syncthreads();
        // stage x tile: 64 tokens x 64 k, fp32 -> bf16 (float4 loads, 8B LDS writes)
        #pragma unroll
        for (int it = 0; it < 4; it++) {
            int f = it * 256 + tid;            // 1024 float4 units
            int row = f >> 4, c4 = (f & 15) * 4;
            float4 v = *(const float4*)(xbase + row * KDIM + kk * 64 + c4);
            ushort4 o; o.x = f2bf(v.x); o.y = f2bf(v.y); o.z = f2bf(v.z); o.w = f2bf(v.w);
            *(ushort4*)&sm.g.xs[row][c4] = o;
        }
        // stage wT tile: 192 head-cols x 64 k (bf16 16B loads, coalesced in k)
        #pragma unroll
        for (int it = 0; it < 6; it++) {
            int task = it * 256 + tid;         // 1536 = 192 cols x 8 k-octets
            int ko = task & 7, cp = task >> 3;
            int gcol = (cp >> 6) * 512 + h * 64 + (cp & 63);  // q/k/v chunk select
            *(short8*)&sm.g.wT[cp][ko * 8] =
                *(const short8*)(wqkvT + (size_t)gcol * KDIM + kk * 64 + ko * 8);
        }
        __syncthreads();
        #pragma unroll
        for (int kh = 0; kh < 2; kh++) {
            short8 af = *(const short8*)&sm.g.xs[wv * 16 + l16][kh * 32 + quad * 8];
            #pragma unroll
            for (int ct = 0; ct < 12; ct++) {
                short8 bf = *(const short8*)&sm.g.wT[ct * 16 + l16][kh * 32 + quad * 8];
                acc[ct] = __builtin_amdgcn_mfma_f32_16x16x32_bf16(af, bf, acc[ct], 0, 0, 0);
            }
        }
    }

    unsigned short* obase = attn_out + (size_t)bm * NTOK * 512 + h * 64;
    const bool focus = mask[b] != 0;

    if (focus) {
        // eye mask -> softmax is one-hot -> out == v exactly (tiles 8..11)
        #pragma unroll
        for (int ct = 8; ct < 12; ct++)
            #pragma unroll
            for (int r = 0; r < 4; r++) {
                int token = wv * 16 + quad * 4 + r;
                obase[(size_t)token * 512 + (ct - 8) * 16 + l16] = f2bf(acc[ct][r]);
            }
        return;
    }

    __syncthreads();   // all waves done reading sm.g before aliased sm.a writes

    // ---- write q (scale+rotary), k (rotary) row-major; v transposed ----
    const float L2T_32 = 0.41524101186092029f;  // log2(10000)/32
    #pragma unroll
    for (int ct = 0; ct < 8; ct++) {
        int d = (ct & 3) * 16 + l16;
        bool isq = ct < 4;
        float invf = exp2f(-(float)(d >> 1) * L2T_32);     // theta^(-2p/64)
        float sgn = (d & 1) ? 1.f : -1.f;                   // rotate_half sign
        #pragma unroll
        for (int r = 0; r < 4; r++) {
            float v0 = acc[ct][r] * (isq ? 0.125f : 1.f);   // q scale = DH^-0.5
            float par = __shfl_xor(v0, 1);                  // pair partner d^1
            int token = wv * 16 + quad * 4 + r;
            float s, c;
            __sincosf(token * invf, &s, &c);
            float o = v0 * c + sgn * par * s;
            if (isq) sm.a.qs[token][d] = f2bf(o);
            else     sm.a.ks[token][d] = f2bf(o);
        }
    }
    #pragma unroll
    for (int ct = 8; ct < 12; ct++) {
        int d = (ct - 8) * 16 + l16;
        #pragma unroll
        for (int r = 0; r < 4; r++)
            sm.a.vt[d][wv * 16 + quad * 4 + r] = f2bf(acc[ct][r]);
    }
    __syncthreads();

    // ---- sim = q k^T : wave w -> rows 16w..16w+15, 4 col tiles, K=64 ----
    floatx4 s4[4];
    #pragma unroll
    for (int i = 0; i < 4; i++) s4[i] = floatx4{0.f, 0.f, 0.f, 0.f};
    #pragma unroll
    for (int kh = 0; kh < 2; kh++) {
        short8 af = *(const short8*)&sm.a.qs[wv * 16 + l16][kh * 32 + quad * 8];
        #pragma unroll
        for (int jt = 0; jt < 4; jt++) {
            short8 bf = *(const short8*)&sm.a.ks[jt * 16 + l16][kh * 32 + quad * 8];
            s4[jt] = __builtin_amdgcn_mfma_f32_16x16x32_bf16(af, bf, s4[jt], 0, 0, 0);
        }
    }

    // ---- +pos_bias, row softmax (rows live in 16-lane groups x 4 tiles) ----
    const float* pb = pos_bias + h * (64 * 64);
    #pragma unroll
    for (int r = 0; r < 4; r++) {
        int i = wv * 16 + quad * 4 + r;
        float vals[4];
        #pragma unroll
        for (int jt = 0; jt < 4; jt++)
            vals[jt] = s4[jt][r] + pb[i * 64 + jt * 16 + l16];
        float mx = fmaxf(fmaxf(vals[0], vals[1]), fmaxf(vals[2], vals[3]));
        #pragma unroll
        for (int off = 1; off < 16; off <<= 1)
            mx = fmaxf(mx, __shfl_xor(mx, off));
        float sum = 0.f;
        #pragma unroll
        for (int jt = 0; jt < 4; jt++) { vals[jt] = __expf(vals[jt] - mx); sum += vals[jt]; }
        #pragma unroll
        for (int off = 1; off < 16; off <<= 1)
            sum += __shfl_xor(sum, off);
        float inv = 1.f / sum;
        #pragma unroll
        for (int jt = 0; jt < 4; jt++)
            sm.a.at[i][jt * 16 + l16] = f2bf(vals[jt] * inv);
    }
    __syncthreads();

    // ---- out = attn @ v ----
    floatx4 o4[4];
    #pragma unroll
    for (int i = 0; i < 4; i++) o4[i] = floatx4{0.f, 0.f, 0.f, 0.f};
    #pragma unroll
    for (int kh = 0; kh < 2; kh++) {
        short8 af = *(const short8*)&sm.a.at[wv * 16 + l16][kh * 32 + quad * 8];
        #pragma unroll
        for (int dt = 0; dt < 4; dt++) {
            short8 bf = *(const short8*)&sm.a.vt[dt * 16 + l16][kh * 32 + quad * 8];
            o4[dt] = __builtin_amdgcn_mfma_f32_16x16x32_bf16(af, bf, o4[dt], 0, 0, 0);
        }
    }
    #pragma unroll
    for (int dt = 0; dt < 4; dt++)
        #pragma unroll
        for (int r = 0; r < 4; r++) {
            int token = wv * 16 + quad * 4 + r;
            obase[(size_t)token * 512 + dt * 16 + l16] = f2bf(o4[dt][r]);
        }
}

// ---------------------------------------------------------------------------
// Output GEMM: (131072 x 512 bf16) @ (512 x 512) -> fp32 d_out.
// Block tile 64 rows x 128 cols, 4 waves, BK=64.
// ---------------------------------------------------------------------------
__global__ __launch_bounds__(256) void out_gemm(
        const unsigned short* __restrict__ attn,   // (131072, 512) bf16
        const unsigned short* __restrict__ woutT,  // (512, 512) bf16, K-major
        float* __restrict__ out)                   // (131072, 512) fp32
{
    const int blk = blockIdx.x;
    const int cb = blk & 3;            // 4 col blocks of 128
    const int rb = blk >> 2;           // 2048 row blocks of 64
    const int tid = threadIdx.x;
    const int wv = tid >> 6, lane = tid & 63, quad = lane >> 4, l16 = lane & 15;

    __shared__ unsigned short as_[64][72];
    __shared__ unsigned short wt_[128][72];

    floatx4 acc[8];
    #pragma unroll
    for (int i = 0; i < 8; i++) acc[i] = floatx4{0.f, 0.f, 0.f, 0.f};

    const unsigned short* abase = attn + (size_t)rb * 64 * 512;

    for (int kk = 0; kk < 8; kk++) {
        if (kk) __syncthreads();
        #pragma unroll
        for (int it = 0; it < 2; it++) {
            int tsk = it * 256 + tid;          // 512 = 64 rows x 8 k-octets
            int row = tsk >> 3, ko = tsk & 7;
            *(short8*)&as_[row][ko * 8] =
                *(const short8*)(abase + (size_t)row * 512 + kk * 64 + ko * 8);
        }
        #pragma unroll
        for (int it = 0; it < 4; it++) {
            int tsk = it * 256 + tid;          // 1024 = 128 cols x 8 k-octets
            int cp = tsk >> 3, ko = tsk & 7;
            *(short8*)&wt_[cp][ko * 8] =
                *(const short8*)(woutT + (size_t)(cb * 128 + cp) * 512 + kk * 64 + ko * 8);
        }
        __syncthreads();
        #pragma unroll
        for (int kh = 0; kh < 2; kh++) {
            short8 af = *(const short8*)&as_[wv * 16 + l16][kh * 32 + quad * 8];
            #pragma unroll
            for (int ct = 0; ct < 8; ct++) {
                short8 bf = *(const short8*)&wt_[ct * 16 + l16][kh * 32 + quad * 8];
                acc[ct] = __builtin_amdgcn_mfma_f32_16x16x32_bf16(af, bf, acc[ct], 0, 0, 0);
            }
        }
    }
    #pragma unroll
    for (int ct = 0; ct < 8; ct++)
        #pragma unroll
        for (int r = 0; r < 4; r++) {
            int row = rb * 64 + wv * 16 + quad * 4 + r;
            out[(size_t)row * 512 + cb * 128 + ct * 16 + l16] = acc[ct][r];
        }
}

// ---------------------------------------------------------------------------
extern "C" void kernel_launch(void* const* d_in, const int* in_sizes, int n_in,
                              void* d_out, int out_size, void* d_ws, size_t ws_size,
                              hipStream_t stream)
{
    const float* x        = (const float*)d_in[0];   // (2,1024,64,512)
    const float* pos_bias = (const float*)d_in[1];   // (8,64,64)
    const float* w_qkv    = (const float*)d_in[2];   // (512,1536)
    const float* w_out    = (const float*)d_in[3];   // (512,512)
    const int*   mask     = (const int*)d_in[4];     // (2,)
    float* out = (float*)d_out;

    // workspace: attn bf16 (128 MiB) | wqkvT bf16 (1.5 MiB) | woutT bf16 (0.5 MiB)
    unsigned short* attn_ws = (unsigned short*)d_ws;
    unsigned short* wqkvT   = attn_ws + (size_t)NBM * NTOK * 512;
    unsigned short* woutT   = wqkvT + (size_t)1536 * 512;

    dim3 t256(256);
    transpose_w<<<dim3(16, 48), t256, 0, stream>>>(w_qkv, wqkvT, 512, 1536);
    transpose_w<<<dim3(16, 16), t256, 0, stream>>>(w_out, woutT, 512, 512);
    fused_qkv_attn<<<NBM * NHEAD, t256, 0, stream>>>(x, pos_bias, wqkvT, mask, attn_ws);
    out_gemm<<<NBM * 4, t256, 0, stream>>>(attn_ws, woutT, out);
}

// Round 2
// 957.714 us; speedup vs baseline: 1.4176x; 1.4176x over previous
//
#include <hip/hip_runtime.h>

// b=2, m=1024, n=64 tokens, DIM=512, HEADS=8, DIM_HEAD=64, HIDDEN=512.
// M = b*m*n = 131072 flattened rows; K = 512; QKV N = 1536; OUT N = 512.
#define MROWS 131072
#define KDIM  512
#define NQKV  1536
#define NHEAD 8

typedef __attribute__((ext_vector_type(8))) short short8;   // 8 bf16 = 4 VGPRs
typedef __attribute__((ext_vector_type(4))) float floatx4;  // MFMA C/D frag

__device__ __forceinline__ unsigned short f2bf(float f) {
    union { float f; unsigned u; } v; v.f = f;
    unsigned r = v.u + 0x7FFFu + ((v.u >> 16) & 1u);
    return (unsigned short)(r >> 16);
}
__device__ __forceinline__ float bf2f(unsigned short u) {
    union { unsigned u; float f; } v; v.u = ((unsigned)u) << 16; return v.f;
}
__device__ __forceinline__ void gld_lds16(const unsigned short* g, unsigned short* l) {
    __builtin_amdgcn_global_load_lds(
        (const __attribute__((address_space(1))) void*)g,
        (__attribute__((address_space(3))) void*)l, 16, 0, 0);
}

// ---------------------------------------------------------------------------
// x fp32 -> bf16, 8 elems/thread (32B load, 16B store).
// ---------------------------------------------------------------------------
__global__ __launch_bounds__(256) void conv_bf16(const float* __restrict__ x,
                                                 unsigned short* __restrict__ xb) {
    size_t i = (size_t)blockIdx.x * 256 + threadIdx.x;
    float4 a = ((const float4*)x)[i * 2], b = ((const float4*)x)[i * 2 + 1];
    short8 o;
    o[0] = (short)f2bf(a.x); o[1] = (short)f2bf(a.y);
    o[2] = (short)f2bf(a.z); o[3] = (short)f2bf(a.w);
    o[4] = (short)f2bf(b.x); o[5] = (short)f2bf(b.y);
    o[6] = (short)f2bf(b.z); o[7] = (short)f2bf(b.w);
    ((short8*)xb)[i] = o;
}

// ---------------------------------------------------------------------------
// Transpose fp32 weight (K x C) -> bf16 wT (C x K); cols < qcols scaled 0.125
// (folds the q scale DIM_HEAD^-0.5 into the weights — exact in bf16).
// ---------------------------------------------------------------------------
__global__ __launch_bounds__(256) void transpose_w(const float* __restrict__ w,
                                                   unsigned short* __restrict__ wT,
                                                   int K, int C, int qcols) {
    __shared__ float tile[32][33];
    int kb = blockIdx.x * 32, cb = blockIdx.y * 32;
    int tx = threadIdx.x & 31, ty = threadIdx.x >> 5;
    for (int i = ty; i < 32; i += 8)
        tile[i][tx] = w[(size_t)(kb + i) * C + cb + tx];
    __syncthreads();
    for (int i = ty; i < 32; i += 8) {
        float s = (cb + i < qcols) ? 0.125f : 1.f;
        wT[(size_t)(cb + i) * K + kb + tx] = f2bf(tile[tx][i] * s);
    }
}

// ---------------------------------------------------------------------------
// m97-style GEMM: (Mr x 512 bf16) @ (N x 512 bf16, K-major)^T -> (Mr x N).
// 128x128 block tile, BK=64, 4 waves (2x2), global_load_lds width 16.
// grid = (N/128, Mr/128)  — cb fastest so the 1.5 MB B stays L2-hot.
// ---------------------------------------------------------------------------
template <int N, bool OUT_BF16>
__global__ __launch_bounds__(256) void gemm128(
        const unsigned short* __restrict__ A,   // (Mr, 512) bf16
        const unsigned short* __restrict__ B,   // (N, 512) bf16 K-major
        void* __restrict__ Cp)
{
    const int cb = blockIdx.x, rb = blockIdx.y;
    const int tid = threadIdx.x;
    const int wv = tid >> 6, lane = tid & 63, quad = lane >> 4, l16 = lane & 15;

    __shared__ unsigned short As[128 * 64];   // 16 KB, unpadded (gld_lds order)
    __shared__ unsigned short Bs[128 * 64];   // 16 KB

    floatx4 acc[16];
    #pragma unroll
    for (int i = 0; i < 16; i++) acc[i] = floatx4{0.f, 0.f, 0.f, 0.f};

    const unsigned short* Ab = A + (size_t)rb * 128 * KDIM;
    const unsigned short* Bb = B + (size_t)cb * 128 * KDIM;
    const int wr = (wv & 1) * 64, wc = (wv >> 1) * 64;

    for (int kk = 0; kk < 8; kk++) {
        if (kk) __syncthreads();
        #pragma unroll
        for (int s = 0; s < 4; s++) {
            int seg = wv * 4 + s;              // 16 x 1KB segments per tile
            int g = seg * 64 + lane;           // 16B granule id
            int row = g >> 3, c8 = (g & 7) * 8;
            gld_lds16(Ab + (size_t)row * KDIM + kk * 64 + c8, As + seg * 512);
            gld_lds16(Bb + (size_t)row * KDIM + kk * 64 + c8, Bs + seg * 512);
        }
        __syncthreads();
        #pragma unroll
        for (int kh = 0; kh < 2; kh++) {
            short8 a4[4], b4[4];
            #pragma unroll
            for (int i = 0; i < 4; i++) {
                a4[i] = *(const short8*)&As[(wr + i * 16 + l16) * 64 + kh * 32 + quad * 8];
                b4[i] = *(const short8*)&Bs[(wc + i * 16 + l16) * 64 + kh * 32 + quad * 8];
            }
            #pragma unroll
            for (int ri = 0; ri < 4; ri++)
                #pragma unroll
                for (int ci = 0; ci < 4; ci++)
                    acc[ri * 4 + ci] = __builtin_amdgcn_mfma_f32_16x16x32_bf16(
                        a4[ri], b4[ci], acc[ri * 4 + ci], 0, 0, 0);
        }
    }

    #pragma unroll
    for (int ri = 0; ri < 4; ri++)
        #pragma unroll
        for (int ci = 0; ci < 4; ci++)
            #pragma unroll
            for (int r = 0; r < 4; r++) {
                size_t row = (size_t)rb * 128 + wr + ri * 16 + quad * 4 + r;
                int col = cb * 128 + wc + ci * 16 + l16;
                if constexpr (OUT_BF16)
                    ((unsigned short*)Cp)[row * N + col] = f2bf(acc[ri * 4 + ci][r]);
                else
                    ((float*)Cp)[row * N + col] = acc[ri * 4 + ci][r];
            }
}

// ---------------------------------------------------------------------------
// Attention per (bm, head): rotary applied on q/k load (pairs are adjacent in
// the short8 — no shuffles), sim = q k^T + pos_bias, softmax, out = attn @ v.
// focus batch: out == v exactly (eye mask -> one-hot softmax) -> plain copy.
// ---------------------------------------------------------------------------
__global__ __launch_bounds__(256) void attn_kernel(
        const unsigned short* __restrict__ qkv,   // (rows, 1536) strip-local
        const float* __restrict__ pos_bias,       // (8, 64, 64)
        const int* __restrict__ mask,             // (2,)
        unsigned short* __restrict__ attn_out,    // (rows, 512) strip-local
        int bm0)                                  // global bm offset of strip
{
    const int blk = blockIdx.x;
    const int h = blk & 7, lbm = blk >> 3;
    const int b = (bm0 + lbm) >> 10;
    const int tid = threadIdx.x;
    const int wv = tid >> 6, lane = tid & 63, quad = lane >> 4, l16 = lane & 15;

    const unsigned short* qb = qkv + (size_t)lbm * 64 * NQKV + h * 64;
    unsigned short* ob = attn_out + (size_t)lbm * 64 * 512 + h * 64;

    if (mask[b] != 0) {   // focus: out = v
        #pragma unroll
        for (int it = 0; it < 2; it++) {
            int tsk = it * 256 + tid;
            int token = tsk >> 3, o8 = (tsk & 7) * 8;
            *(short8*)&ob[(size_t)token * 512 + o8] =
                *(const short8*)&qb[(size_t)token * NQKV + 1024 + o8];
        }
        return;
    }

    __shared__ unsigned short qs[64][72];
    __shared__ unsigned short ks[64][72];
    __shared__ unsigned short vt[64][72];
    __shared__ unsigned short at[64][72];

    const float L2T_32 = 0.41524101186092029f;   // log2(10000)/32
    #pragma unroll
    for (int it = 0; it < 2; it++) {
        int tsk = it * 256 + tid;
        int token = tsk >> 3, oct = tsk & 7;
        short8 qv = *(const short8*)&qb[(size_t)token * NQKV + oct * 8];
        short8 kv = *(const short8*)&qb[(size_t)token * NQKV + 512 + oct * 8];
        short8 qo, ko;
        #pragma unroll
        for (int p = 0; p < 4; p++) {
            float invf = exp2f(-(float)(oct * 4 + p) * L2T_32);
            float s, c;
            __sincosf(token * invf, &s, &c);
            float qe = bf2f((unsigned short)qv[2 * p]), qd = bf2f((unsigned short)qv[2 * p + 1]);
            float ke = bf2f((unsigned short)kv[2 * p]), kd = bf2f((unsigned short)kv[2 * p + 1]);
            qo[2 * p]     = (short)f2bf(qe * c - qd * s);
            qo[2 * p + 1] = (short)f2bf(qd * c + qe * s);
            ko[2 * p]     = (short)f2bf(ke * c - kd * s);
            ko[2 * p + 1] = (short)f2bf(kd * c + ke * s);
        }
        *(short8*)&qs[token][oct * 8] = qo;
        *(short8*)&ks[token][oct * 8] = ko;
        short8 vv = *(const short8*)&qb[(size_t)token * NQKV + 1024 + oct * 8];
        #pragma unroll
        for (int j = 0; j < 8; j++) vt[oct * 8 + j][token] = (unsigned short)vv[j];
    }
    __syncthreads();

    // sim = q k^T (wave w -> rows 16w..16w+15), K = 64
    floatx4 s4[4];
    #pragma unroll
    for (int i = 0; i < 4; i++) s4[i] = floatx4{0.f, 0.f, 0.f, 0.f};
    #pragma unroll
    for (int kh = 0; kh < 2; kh++) {
        short8 af = *(const short8*)&qs[wv * 16 + l16][kh * 32 + quad * 8];
        #pragma unroll
        for (int jt = 0; jt < 4; jt++) {
            short8 bf = *(const short8*)&ks[jt * 16 + l16][kh * 32 + quad * 8];
            s4[jt] = __builtin_amdgcn_mfma_f32_16x16x32_bf16(af, bf, s4[jt], 0, 0, 0);
        }
    }

    const float* pb = pos_bias + h * (64 * 64);
    #pragma unroll
    for (int r = 0; r < 4; r++) {
        int i = wv * 16 + quad * 4 + r;
        float vals[4];
        #pragma unroll
        for (int jt = 0; jt < 4; jt++)
            vals[jt] = s4[jt][r] + pb[i * 64 + jt * 16 + l16];
        float mx = fmaxf(fmaxf(vals[0], vals[1]), fmaxf(vals[2], vals[3]));
        #pragma unroll
        for (int off = 1; off < 16; off <<= 1)
            mx = fmaxf(mx, __shfl_xor(mx, off));
        float sum = 0.f;
        #pragma unroll
        for (int jt = 0; jt < 4; jt++) { vals[jt] = __expf(vals[jt] - mx); sum += vals[jt]; }
        #pragma unroll
        for (int off = 1; off < 16; off <<= 1)
            sum += __shfl_xor(sum, off);
        float inv = 1.f / sum;
        #pragma unroll
        for (int jt = 0; jt < 4; jt++)
            at[i][jt * 16 + l16] = f2bf(vals[jt] * inv);
    }
    __syncthreads();

    floatx4 o4[4];
    #pragma unroll
    for (int i = 0; i < 4; i++) o4[i] = floatx4{0.f, 0.f, 0.f, 0.f};
    #pragma unroll
    for (int kh = 0; kh < 2; kh++) {
        short8 af = *(const short8*)&at[wv * 16 + l16][kh * 32 + quad * 8];
        #pragma unroll
        for (int dt = 0; dt < 4; dt++) {
            short8 bf = *(const short8*)&vt[dt * 16 + l16][kh * 32 + quad * 8];
            o4[dt] = __builtin_amdgcn_mfma_f32_16x16x32_bf16(af, bf, o4[dt], 0, 0, 0);
        }
    }
    #pragma unroll
    for (int dt = 0; dt < 4; dt++)
        #pragma unroll
        for (int r = 0; r < 4; r++) {
            int token = wv * 16 + quad * 4 + r;
            ob[(size_t)token * 512 + dt * 16 + l16] = f2bf(o4[dt][r]);
        }
}

// ---------------------------------------------------------------------------
extern "C" void kernel_launch(void* const* d_in, const int* in_sizes, int n_in,
                              void* d_out, int out_size, void* d_ws, size_t ws_size,
                              hipStream_t stream)
{
    const float* x        = (const float*)d_in[0];
    const float* pos_bias = (const float*)d_in[1];
    const float* w_qkv    = (const float*)d_in[2];
    const float* w_out    = (const float*)d_in[3];
    const int*   mask     = (const int*)d_in[4];
    float* out = (float*)d_out;

    // ws layout: [wqkvT 1536x512][woutT 512x512][xb Rx512][qkv Rx1536][attn Rx512]
    unsigned short* wqkvT = (unsigned short*)d_ws;
    unsigned short* woutT = wqkvT + (size_t)NQKV * KDIM;
    size_t fixed_b = ((size_t)NQKV * KDIM + (size_t)KDIM * KDIM) * 2;

    int R = MROWS;   // strip rows; shrink to fit ws (same every call -> graph-safe)
    while (R > 128 && (size_t)R * 5120 + fixed_b > ws_size) R >>= 1;
    unsigned short* xb   = woutT + (size_t)KDIM * KDIM;
    unsigned short* qkvb = xb + (size_t)R * KDIM;
    unsigned short* attb = qkvb + (size_t)R * NQKV;
    int nstrip = MROWS / R;

    dim3 t256(256);
    transpose_w<<<dim3(16, 48), t256, 0, stream>>>(w_qkv, wqkvT, KDIM, NQKV, 512);
    transpose_w<<<dim3(16, 16), t256, 0, stream>>>(w_out, woutT, KDIM, KDIM, 0);

    for (int s = 0; s < nstrip; s++) {
        const float* xs = x + (size_t)s * R * KDIM;
        conv_bf16<<<R / 4, t256, 0, stream>>>(xs, xb);
        gemm128<NQKV, true><<<dim3(NQKV / 128, R / 128), t256, 0, stream>>>(xb, wqkvT, qkvb);
        attn_kernel<<<(R / 64) * NHEAD, t256, 0, stream>>>(qkvb, pos_bias, mask, attb, s * (R / 64));
        gemm128<512, false><<<dim3(4, R / 128), t256, 0, stream>>>(attb, woutT, out + (size_t)s * R * KDIM);
    }
}